// Round 1
// baseline (329.776 us; speedup 1.0000x reference)
//
#include <hip/hip_runtime.h>
#include <hip/hip_bf16.h>
#include <math.h>

#define NBOX   16384
#define NPRE   1024
#define NPOST  512
#define NMS_TH 0.8f
#define DEN_EPS 1e-8f
#define JCHUNK 2048

typedef unsigned long long ull;

// ---------------- K1: scores -> sortable keys, zero ranks ----------------
// key = (ordered_u32(score) << 14) | (16383 - i): u64 '>' == top_k order
__global__ void k_keys(const float* __restrict__ cls, ull* __restrict__ keys,
                       int* __restrict__ rank) {
  int gid = blockIdx.x * 256 + threadIdx.x;          // over B*NBOX
  int i = gid & (NBOX - 1);
  float l0 = cls[(size_t)gid * 3 + 0];
  float l1 = cls[(size_t)gid * 3 + 1];
  float l2 = cls[(size_t)gid * 3 + 2];
  float s = fmaxf(l0, fmaxf(l1, l2));
  unsigned u = __float_as_uint(s);
  u = (u & 0x80000000u) ? ~u : (u | 0x80000000u);    // monotonic map
  keys[gid] = ((ull)u << 14) | (ull)(16383 - i);
  rank[gid] = 0;
}

// ---------------- K2a: partial ranks (count greater keys) ----------------
__global__ void k_rank(const ull* __restrict__ keys, int* __restrict__ rank) {
  __shared__ ull tile[JCHUNK];
  int b  = blockIdx.x >> 6;                          // NBOX/256 == 64 chunks
  int ic = blockIdx.x & 63;
  int tid = threadIdx.x;
  int i = ic * 256 + tid;
  const ull* kb = keys + (size_t)b * NBOX;
  ull my = kb[i];
  int jbase = blockIdx.y * JCHUNK;
#pragma unroll
  for (int t = 0; t < JCHUNK / 256; ++t)
    tile[tid + t * 256] = kb[jbase + tid + t * 256];
  __syncthreads();
  int cnt = 0;
  const ulonglong2* t2 = (const ulonglong2*)tile;
#pragma unroll 4
  for (int j = 0; j < JCHUNK / 2; ++j) {
    ulonglong2 kk = t2[j];
    cnt += (kk.x > my) ? 1 : 0;
    cnt += (kk.y > my) ? 1 : 0;
  }
  atomicAdd(&rank[(size_t)b * NBOX + i], cnt);
}

// ---------------- K2b: select top-NPRE, build per-box geometry -----------
// binfo row (16 floats): x,y,dx,dy,cos,sin,cx[4],cy[4],circumrad,area
__global__ void k_select(const float* __restrict__ box, const int* __restrict__ rank,
                         int* __restrict__ topi, float* __restrict__ binfo) {
  int gid = blockIdx.x * 256 + threadIdx.x;
  int b = gid >> 14;
  int i = gid & (NBOX - 1);
  int r = rank[gid];
  if (r >= NPRE) return;
  topi[b * NPRE + r] = i;
  const float* bp = box + (size_t)gid * 7;
  float x = bp[0], y = bp[1], dx = bp[3], dy = bp[4], ry = bp[6];
  float c = cosf(ry), s = sinf(ry);
  float* o = binfo + ((size_t)b * NPRE + r) * 16;
  o[0] = x; o[1] = y; o[2] = dx; o[3] = dy; o[4] = c; o[5] = s;
  const float offx[4] = {0.5f, -0.5f, -0.5f, 0.5f};
  const float offy[4] = {0.5f, 0.5f, -0.5f, -0.5f};
#pragma unroll
  for (int k = 0; k < 4; ++k) {
    float lx = dx * offx[k], ly = dy * offy[k];
    o[6 + k]  = x + lx * c - ly * s;
    o[10 + k] = y + lx * s + ly * c;
  }
  o[14] = 0.5f * sqrtf(dx * dx + dy * dy);
  o[15] = dx * dy;
}

// ---------------- per-pair rotated IoU > thresh (reference math) ----------
__device__ bool iou_gt(const float* __restrict__ Ab, const float* __restrict__ Bb) {
  float ax = Ab[0], ay = Ab[1], bx = Bb[0], by = Bb[1];
  float ddx = ax - bx, ddy = ay - by;
  float rr = Ab[14] + Bb[14] + 1e-3f;
  if (ddx * ddx + ddy * ddy > rr * rr) return false;   // disjoint => iou 0
  float aA = Ab[15], aB = Bb[15];
  float mn = fminf(aA, aB), mx = fmaxf(aA, aB);
  if (mn <= NMS_TH * mx) return false;                 // iou <= min/max <= 0.8

  float acx[4], acy[4], bcx[4], bcy[4];
#pragma unroll
  for (int k = 0; k < 4; ++k) {
    acx[k] = Ab[6 + k]; acy[k] = Ab[10 + k];
    bcx[k] = Bb[6 + k]; bcy[k] = Bb[10 + k];
  }
  float px[24], py[24];
  int mfl[24];
#pragma unroll
  for (int p = 0; p < 4; ++p) {
    float A0x = acx[p], A0y = acy[p];
    float DAx = acx[(p + 1) & 3] - A0x, DAy = acy[(p + 1) & 3] - A0y;
#pragma unroll
    for (int q = 0; q < 4; ++q) {
      float B0x = bcx[q], B0y = bcy[q];
      float DBx = bcx[(q + 1) & 3] - B0x, DBy = bcy[(q + 1) & 3] - B0y;
      float den = DAx * DBy - DAy * DBx;
      float dxx = B0x - A0x, dyy = B0y - A0y;
      bool dok = fabsf(den) > DEN_EPS;
      float dens = dok ? den : 1.0f;
      float t = (dxx * DBy - dyy * DBx) / dens;
      float u = (dxx * DAy - dyy * DAx) / dens;
      bool ok = dok && t >= 0.f && t <= 1.f && u >= 0.f && u <= 1.f;
      int k = p * 4 + q;
      px[k] = A0x + t * DAx;
      py[k] = A0y + t * DAy;
      mfl[k] = ok ? 1 : 0;
    }
  }
#pragma unroll
  for (int k = 0; k < 4; ++k) {       // corners of A in B
    float relx = acx[k] - bx, rely = acy[k] - by;
    float qx =  relx * Bb[4] + rely * Bb[5];
    float qy = -relx * Bb[5] + rely * Bb[4];
    bool in_ = (fabsf(qx) <= Bb[2] * 0.5f + 1e-5f) && (fabsf(qy) <= Bb[3] * 0.5f + 1e-5f);
    px[16 + k] = acx[k]; py[16 + k] = acy[k]; mfl[16 + k] = in_ ? 1 : 0;
  }
#pragma unroll
  for (int k = 0; k < 4; ++k) {       // corners of B in A
    float relx = bcx[k] - ax, rely = bcy[k] - ay;
    float qx =  relx * Ab[4] + rely * Ab[5];
    float qy = -relx * Ab[5] + rely * Ab[4];
    bool in_ = (fabsf(qx) <= Ab[2] * 0.5f + 1e-5f) && (fabsf(qy) <= Ab[3] * 0.5f + 1e-5f);
    px[20 + k] = bcx[k]; py[20 + k] = bcy[k]; mfl[20 + k] = in_ ? 1 : 0;
  }
  int cnt = 0; float sx = 0.f, sy = 0.f;
#pragma unroll
  for (int k = 0; k < 24; ++k)
    if (mfl[k]) { cnt++; sx += px[k]; sy += py[k]; }
  float inv = 1.0f / (float)(cnt > 1 ? cnt : 1);
  float cx0 = sx * inv, cy0 = sy * inv;
  float ang[24];
#pragma unroll
  for (int k = 0; k < 24; ++k)
    ang[k] = mfl[k] ? atan2f(py[k] - cy0, px[k] - cx0) : 1e9f;
  // stable insertion sort by angle (== jnp.argsort stable)
  for (int k = 1; k < 24; ++k) {
    float ka = ang[k], kx = px[k], ky = py[k]; int km = mfl[k];
    int j = k - 1;
    while (j >= 0 && ang[j] > ka) {
      ang[j + 1] = ang[j]; px[j + 1] = px[j]; py[j + 1] = py[j]; mfl[j + 1] = mfl[j];
      --j;
    }
    ang[j + 1] = ka; px[j + 1] = kx; py[j + 1] = ky; mfl[j + 1] = km;
  }
  // poly[k] = msk ? pts : first   (first == pts_s[0] == px[0])
  float p0x = px[0], p0y = py[0];
  float ssum = 0.f;
  float prx = p0x, pry = p0y;
  for (int k = 1; k < 24; ++k) {
    float cxk = mfl[k] ? px[k] : p0x;
    float cyk = mfl[k] ? py[k] : p0y;
    ssum += prx * cyk - pry * cxk;
    prx = cxk; pry = cyk;
  }
  ssum += prx * p0y - pry * p0x;
  float inter = 0.5f * fabsf(ssum);
  float uni = aA + aB - inter;
  float iou = inter / fmaxf(uni, 1e-6f);
  return iou > NMS_TH;
}

// ---------------- K3: IoU bitmask, one wave per (i, 64-col word) ----------
__global__ void k_ioumask(const float* __restrict__ binfo, ull* __restrict__ mask) {
  int wv = (blockIdx.x * 256 + threadIdx.x) >> 6;
  int lane = threadIdx.x & 63;
  int w = wv & 15;
  int i = (wv >> 4) & (NPRE - 1);
  int b = wv >> 14;
  int j = w * 64 + lane;
  bool pred = false;
  if (w * 64 + 63 > i) {                 // some lane has j > i
    const float* base = binfo + (size_t)b * NPRE * 16;
    if (j > i) pred = iou_gt(base + (size_t)i * 16, base + (size_t)j * 16);
  }
  ull bal = __ballot(pred);
  if (lane == 0) mask[((size_t)b * NPRE + i) * 16 + w] = bal;
}

// ---------------- K4: greedy NMS, one wave per batch ----------------------
__global__ void k_nms(const ull* __restrict__ mask, ull* __restrict__ remv_out) {
  int b = blockIdx.x;
  int lane = threadIdx.x;
  const ull* M = mask + (size_t)b * NPRE * 16;
  ull remv = 0;
  ull r0 = (lane < 16) ? M[(size_t)0 * 16 + lane] : 0ULL;
  ull r1 = (lane < 16) ? M[(size_t)1 * 16 + lane] : 0ULL;
  ull r2 = (lane < 16) ? M[(size_t)2 * 16 + lane] : 0ULL;
  ull r3 = (lane < 16) ? M[(size_t)3 * 16 + lane] : 0ULL;
  for (int i = 0; i < NPRE; i += 4) {
    {
      ull rw = __shfl(remv, i >> 6, 64);
      if (!((rw >> (i & 63)) & 1ULL)) remv |= r0;
      r0 = (lane < 16 && i + 4 < NPRE) ? M[(size_t)(i + 4) * 16 + lane] : 0ULL;
    }
    {
      int ii = i + 1;
      ull rw = __shfl(remv, ii >> 6, 64);
      if (!((rw >> (ii & 63)) & 1ULL)) remv |= r1;
      r1 = (lane < 16 && ii + 4 < NPRE) ? M[(size_t)(ii + 4) * 16 + lane] : 0ULL;
    }
    {
      int ii = i + 2;
      ull rw = __shfl(remv, ii >> 6, 64);
      if (!((rw >> (ii & 63)) & 1ULL)) remv |= r2;
      r2 = (lane < 16 && ii + 4 < NPRE) ? M[(size_t)(ii + 4) * 16 + lane] : 0ULL;
    }
    {
      int ii = i + 3;
      ull rw = __shfl(remv, ii >> 6, 64);
      if (!((rw >> (ii & 63)) & 1ULL)) remv |= r3;
      r3 = (lane < 16 && ii + 4 < NPRE) ? M[(size_t)(ii + 4) * 16 + lane] : 0ULL;
    }
  }
  if (lane < 16) remv_out[b * 16 + lane] = remv;
}

// ---------------- K5: compact survivors, gather outputs -------------------
__global__ void k_final(const float* __restrict__ box, const float* __restrict__ cls,
                        const int* __restrict__ topi, const ull* __restrict__ remv,
                        float* __restrict__ out, int B) {
  int b = blockIdx.x;
  int p = threadIdx.x;                 // 0..1023
  int lane = p & 63, wid = p >> 6;
  ull rw = remv[b * 16 + wid];
  int alive = ((rw >> lane) & 1ULL) ? 0 : 1;
  int v = alive;
#pragma unroll
  for (int off = 1; off < 64; off <<= 1) {
    int t = __shfl_up(v, off, 64);
    if (lane >= off) v += t;
  }
  __shared__ int wtot[16], woff[17];
  if (lane == 63) wtot[wid] = v;
  __syncthreads();
  if (p == 0) {
    int acc = 0;
    for (int t = 0; t < 16; ++t) { woff[t] = acc; acc += wtot[t]; }
    woff[16] = acc;
  }
  __syncthreads();
  int excl = v - alive + woff[wid];
  int total = woff[16];
  float* rois   = out;
  float* scores = out + (size_t)B * NPOST * 7;
  float* labels = scores + (size_t)B * NPOST;
  float* logits = labels + (size_t)B * NPOST;
  if (alive && excl < NPOST) {
    int s = excl;
    int orig = topi[b * NPRE + p];
    const float* bb = box + ((size_t)b * NBOX + orig) * 7;
    float* ro = rois + ((size_t)b * NPOST + s) * 7;
#pragma unroll
    for (int c = 0; c < 7; ++c) ro[c] = bb[c];
    const float* cc = cls + ((size_t)b * NBOX + orig) * 3;
    float l0 = cc[0], l1 = cc[1], l2 = cc[2];
    float m = fmaxf(l0, fmaxf(l1, l2));
    int lab = (l0 == m) ? 0 : ((l1 == m) ? 1 : 2);   // argmax: first max
    scores[b * NPOST + s] = m;
    labels[b * NPOST + s] = (float)(lab + 1);
    float* lg = logits + ((size_t)b * NPOST + s) * 3;
    lg[0] = l0; lg[1] = l1; lg[2] = l2;
  }
  if (p < NPOST && p >= total) {       // invalid slots: zeros, label 1
    float* ro = rois + ((size_t)b * NPOST + p) * 7;
#pragma unroll
    for (int c = 0; c < 7; ++c) ro[c] = 0.f;
    scores[b * NPOST + p] = 0.f;
    labels[b * NPOST + p] = 1.f;
    float* lg = logits + ((size_t)b * NPOST + p) * 3;
    lg[0] = 0.f; lg[1] = 0.f; lg[2] = 0.f;
  }
}

extern "C" void kernel_launch(void* const* d_in, const int* in_sizes, int n_in,
                              void* d_out, int out_size, void* d_ws, size_t ws_size,
                              hipStream_t stream) {
  const float* box = (const float*)d_in[0];
  const float* cls = (const float*)d_in[1];
  float* out = (float*)d_out;
  int B = in_sizes[0] / (NBOX * 7);    // == 2

  char* w = (char*)d_ws;
  size_t off = 0;
  ull* keys  = (ull*)(w + off);   off += (size_t)B * NBOX * sizeof(ull);
  int* rank  = (int*)(w + off);   off += (size_t)B * NBOX * sizeof(int);
  int* topi  = (int*)(w + off);   off += (size_t)B * NPRE * sizeof(int);
  off = (off + 63) & ~(size_t)63;
  float* binfo = (float*)(w + off); off += (size_t)B * NPRE * 16 * sizeof(float);
  ull* mask  = (ull*)(w + off);   off += (size_t)B * NPRE * 16 * sizeof(ull);
  ull* remv  = (ull*)(w + off);   off += (size_t)B * 16 * sizeof(ull);
  (void)off; (void)ws_size; (void)out_size; (void)n_in;

  hipLaunchKernelGGL(k_keys,    dim3(B * NBOX / 256), dim3(256), 0, stream, cls, keys, rank);
  hipLaunchKernelGGL(k_rank,    dim3(B * (NBOX / 256), NBOX / JCHUNK), dim3(256), 0, stream, keys, rank);
  hipLaunchKernelGGL(k_select,  dim3(B * NBOX / 256), dim3(256), 0, stream, box, rank, topi, binfo);
  hipLaunchKernelGGL(k_ioumask, dim3(B * NPRE * 16 / 4), dim3(256), 0, stream, binfo, mask);
  hipLaunchKernelGGL(k_nms,     dim3(B), dim3(64), 0, stream, mask, remv);
  hipLaunchKernelGGL(k_final,   dim3(B), dim3(1024), 0, stream, box, cls, topi, remv, out, B);
}

// Round 2
// 166.065 us; speedup vs baseline: 1.9858x; 1.9858x over previous
//
#include <hip/hip_runtime.h>
#include <hip/hip_bf16.h>
#include <math.h>

#define NBOX   16384
#define NPRE   1024
#define NPOST  512
#define NMS_TH 0.8f
#define DEN_EPS 1e-8f
#define NCAND  2048          // candidate buffer (top-k + threshold-bucket slack)
#define NBUCK  8192          // 13-bit histogram buckets

typedef unsigned long long ull;

// ---------------- K1: keys + histogram select + compact (one block/batch) ----
// key = (monotonic_u32(score) << 14) | (16383 - i): u64 '>' == top_k order.
// bucket = key >> 33 (top 13 bits of monotonic score). Finds threshold bucket T
// s.t. count(bucket > T) < 1024 <= count(bucket >= T); compacts bucket >= T.
__global__ __launch_bounds__(1024) void k_hist(
    const float* __restrict__ cls, ull* __restrict__ cand,
    unsigned* __restrict__ candCount, unsigned* __restrict__ nz) {
  __shared__ unsigned hist[NBUCK];
  __shared__ unsigned ssum[1024];
  __shared__ unsigned thrT;
  __shared__ unsigned cnt;
  int b = blockIdx.x;
  int t = threadIdx.x;
  nz[b * NPRE + t] = 0u;                       // zero nz for k_ioumask/k_nms
#pragma unroll
  for (int k = 0; k < NBUCK / 1024; ++k) hist[t + k * 1024] = 0u;
  if (t == 0) cnt = 0u;
  __syncthreads();

  ull key[16];
#pragma unroll
  for (int k = 0; k < 16; ++k) {
    int i = k * 1024 + t;
    const float* cc = cls + ((size_t)b * NBOX + i) * 3;
    float s = fmaxf(cc[0], fmaxf(cc[1], cc[2]));
    unsigned u = __float_as_uint(s);
    u = (u & 0x80000000u) ? ~u : (u | 0x80000000u);
    key[k] = ((ull)u << 14) | (ull)(16383 - i);
    atomicAdd(&hist[u >> 19], 1u);
  }
  __syncthreads();

  // per-thread group sum over 8 buckets, then inclusive suffix scan
  unsigned s8 = 0;
#pragma unroll
  for (int k = 0; k < 8; ++k) s8 += hist[t * 8 + k];
  ssum[t] = s8;
  __syncthreads();
  for (int off = 1; off < 1024; off <<= 1) {
    unsigned v = ssum[t] + ((t + off < 1024) ? ssum[t + off] : 0u);
    __syncthreads();
    ssum[t] = v;
    __syncthreads();
  }
  unsigned Sown = ssum[t];
  unsigned Snxt = (t < 1023) ? ssum[t + 1] : 0u;
  if (Sown >= NPRE && Snxt < NPRE) {           // unique boundary group
    unsigned c = Snxt;
    unsigned T = t * 8;
    for (int k = 7; k >= 0; --k) {
      c += hist[t * 8 + k];
      if (c >= NPRE) { T = t * 8 + k; break; }
    }
    thrT = T;
  }
  __syncthreads();
  unsigned T = thrT;
#pragma unroll
  for (int k = 0; k < 16; ++k) {
    unsigned bkt = (unsigned)(key[k] >> 33);
    if (bkt >= T) {
      unsigned pos = atomicAdd(&cnt, 1u);
      if (pos < NCAND) cand[(size_t)b * NCAND + pos] = key[k];
    }
  }
  __syncthreads();
  if (t == 0) candCount[b] = (cnt < NCAND) ? cnt : NCAND;
}

// ---------------- K2: rank candidates, emit topi + per-box geometry ----------
// binfo row (16 floats): x,y,dx,dy,cos,sin,cx[4],cy[4],circumrad,area
__global__ __launch_bounds__(64) void k_ranksel(
    const float* __restrict__ box, const ull* __restrict__ cand,
    const unsigned* __restrict__ candCount,
    int* __restrict__ topi, float* __restrict__ binfo) {
  __shared__ ull lk[NCAND];
  int b = blockIdx.y;
  int tid = threadIdx.x;
  int j = blockIdx.x * 64 + tid;               // 0..2047
  unsigned C = candCount[b];
#pragma unroll
  for (int k = 0; k < NCAND / 64; ++k) {
    int idx = k * 64 + tid;
    lk[idx] = ((unsigned)idx < C) ? cand[(size_t)b * NCAND + idx] : 0ULL;
  }
  __syncthreads();
  ull my = ((unsigned)j < C) ? lk[j] : 0ULL;
  int r = 0;
  const ulonglong2* p2 = (const ulonglong2*)lk;
#pragma unroll 8
  for (int k = 0; k < NCAND / 2; ++k) {
    ulonglong2 kk = p2[k];
    r += (kk.x > my) ? 1 : 0;
    r += (kk.y > my) ? 1 : 0;
  }
  if ((unsigned)j >= C || r >= NPRE) return;
  int i = 16383 - (int)(my & 0x3FFFULL);
  topi[b * NPRE + r] = i;
  const float* bp = box + ((size_t)b * NBOX + i) * 7;
  float x = bp[0], y = bp[1], dx = bp[3], dy = bp[4], ry = bp[6];
  float c = cosf(ry), s = sinf(ry);
  float* o = binfo + ((size_t)b * NPRE + r) * 16;
  o[0] = x; o[1] = y; o[2] = dx; o[3] = dy; o[4] = c; o[5] = s;
  const float offx[4] = {0.5f, -0.5f, -0.5f, 0.5f};
  const float offy[4] = {0.5f, 0.5f, -0.5f, -0.5f};
#pragma unroll
  for (int k = 0; k < 4; ++k) {
    float lx = dx * offx[k], ly = dy * offy[k];
    o[6 + k]  = x + lx * c - ly * s;
    o[10 + k] = y + lx * s + ly * c;
  }
  o[14] = 0.5f * sqrtf(dx * dx + dy * dy);
  o[15] = dx * dy;
}

// ---------------- per-pair rotated IoU > thresh (reference math) ----------
__device__ bool iou_gt(const float* __restrict__ Ab, const float* __restrict__ Bb) {
  float ax = Ab[0], ay = Ab[1], bx = Bb[0], by = Bb[1];
  float ddx = ax - bx, ddy = ay - by;
  float rr = Ab[14] + Bb[14] + 1e-3f;
  if (ddx * ddx + ddy * ddy > rr * rr) return false;   // disjoint => iou 0
  float aA = Ab[15], aB = Bb[15];
  float mn = fminf(aA, aB), mx = fmaxf(aA, aB);
  if (mn <= NMS_TH * mx) return false;                 // iou <= min/max <= 0.8

  float acx[4], acy[4], bcx[4], bcy[4];
#pragma unroll
  for (int k = 0; k < 4; ++k) {
    acx[k] = Ab[6 + k]; acy[k] = Ab[10 + k];
    bcx[k] = Bb[6 + k]; bcy[k] = Bb[10 + k];
  }
  float px[24], py[24];
  int mfl[24];
#pragma unroll
  for (int p = 0; p < 4; ++p) {
    float A0x = acx[p], A0y = acy[p];
    float DAx = acx[(p + 1) & 3] - A0x, DAy = acy[(p + 1) & 3] - A0y;
#pragma unroll
    for (int q = 0; q < 4; ++q) {
      float B0x = bcx[q], B0y = bcy[q];
      float DBx = bcx[(q + 1) & 3] - B0x, DBy = bcy[(q + 1) & 3] - B0y;
      float den = DAx * DBy - DAy * DBx;
      float dxx = B0x - A0x, dyy = B0y - A0y;
      bool dok = fabsf(den) > DEN_EPS;
      float dens = dok ? den : 1.0f;
      float t = (dxx * DBy - dyy * DBx) / dens;
      float u = (dxx * DAy - dyy * DAx) / dens;
      bool ok = dok && t >= 0.f && t <= 1.f && u >= 0.f && u <= 1.f;
      int k = p * 4 + q;
      px[k] = A0x + t * DAx;
      py[k] = A0y + t * DAy;
      mfl[k] = ok ? 1 : 0;
    }
  }
#pragma unroll
  for (int k = 0; k < 4; ++k) {       // corners of A in B
    float relx = acx[k] - bx, rely = acy[k] - by;
    float qx =  relx * Bb[4] + rely * Bb[5];
    float qy = -relx * Bb[5] + rely * Bb[4];
    bool in_ = (fabsf(qx) <= Bb[2] * 0.5f + 1e-5f) && (fabsf(qy) <= Bb[3] * 0.5f + 1e-5f);
    px[16 + k] = acx[k]; py[16 + k] = acy[k]; mfl[16 + k] = in_ ? 1 : 0;
  }
#pragma unroll
  for (int k = 0; k < 4; ++k) {       // corners of B in A
    float relx = bcx[k] - ax, rely = bcy[k] - ay;
    float qx =  relx * Ab[4] + rely * Ab[5];
    float qy = -relx * Ab[5] + rely * Ab[4];
    bool in_ = (fabsf(qx) <= Ab[2] * 0.5f + 1e-5f) && (fabsf(qy) <= Ab[3] * 0.5f + 1e-5f);
    px[20 + k] = bcx[k]; py[20 + k] = bcy[k]; mfl[20 + k] = in_ ? 1 : 0;
  }
  int cnt = 0; float sx = 0.f, sy = 0.f;
#pragma unroll
  for (int k = 0; k < 24; ++k)
    if (mfl[k]) { cnt++; sx += px[k]; sy += py[k]; }
  float inv = 1.0f / (float)(cnt > 1 ? cnt : 1);
  float cx0 = sx * inv, cy0 = sy * inv;
  float ang[24];
#pragma unroll
  for (int k = 0; k < 24; ++k)
    ang[k] = mfl[k] ? atan2f(py[k] - cy0, px[k] - cx0) : 1e9f;
  // stable insertion sort by angle (== jnp.argsort stable)
  for (int k = 1; k < 24; ++k) {
    float ka = ang[k], kx = px[k], ky = py[k]; int km = mfl[k];
    int j = k - 1;
    while (j >= 0 && ang[j] > ka) {
      ang[j + 1] = ang[j]; px[j + 1] = px[j]; py[j + 1] = py[j]; mfl[j + 1] = mfl[j];
      --j;
    }
    ang[j + 1] = ka; px[j + 1] = kx; py[j + 1] = ky; mfl[j + 1] = km;
  }
  float p0x = px[0], p0y = py[0];
  float ssum = 0.f;
  float prx = p0x, pry = p0y;
  for (int k = 1; k < 24; ++k) {
    float cxk = mfl[k] ? px[k] : p0x;
    float cyk = mfl[k] ? py[k] : p0y;
    ssum += prx * cyk - pry * cxk;
    prx = cxk; pry = cyk;
  }
  ssum += prx * p0y - pry * p0x;
  float inter = 0.5f * fabsf(ssum);
  float uni = aA + aB - inter;
  float iou = inter / fmaxf(uni, 1e-6f);
  return iou > NMS_TH;
}

// ---------------- K3: IoU bitmask + nonzero-word bitmap ------------------
__global__ void k_ioumask(const float* __restrict__ binfo, ull* __restrict__ mask,
                          unsigned* __restrict__ nz) {
  int wv = (blockIdx.x * 256 + threadIdx.x) >> 6;
  int lane = threadIdx.x & 63;
  int w = wv & 15;
  int i = (wv >> 4) & (NPRE - 1);
  int b = wv >> 14;
  int j = w * 64 + lane;
  bool pred = false;
  if (w * 64 + 63 > i) {                 // some lane has j > i
    const float* base = binfo + (size_t)b * NPRE * 16;
    if (j > i) pred = iou_gt(base + (size_t)i * 16, base + (size_t)j * 16);
  }
  ull bal = __ballot(pred);
  if (lane == 0 && bal) {
    mask[((size_t)b * NPRE + i) * 16 + w] = bal;
    atomicOr(&nz[b * NPRE + i], 1u << w);
  }
}

// ---------------- K4: sparse greedy NMS, one wave per batch ---------------
// Only rows with nz!=0 can suppress; all others are pass-through.
__global__ __launch_bounds__(64) void k_nms(const ull* __restrict__ mask,
                                            const unsigned* __restrict__ nz,
                                            ull* __restrict__ remv_out) {
  __shared__ ull rf[16];
  int b = blockIdx.x;
  int lane = threadIdx.x;
  for (int w = 0; w < 16; ++w) {
    unsigned v = nz[b * NPRE + w * 64 + lane];
    ull bb = __ballot(v != 0u);
    if (lane == 0) rf[w] = bb;
  }
  __syncthreads();
  ull remv = 0;                          // lane w<16 holds remv word w
  for (int w = 0; w < 16; ++w) {
    ull bb = rf[w];                      // wave-uniform
    while (bb) {
      int i = __ffsll(bb) - 1;
      bb &= bb - 1;
      int row = w * 64 + i;
      ull rw = __shfl(remv, w, 64);      // current remv word w (uniform)
      if (!((rw >> i) & 1ULL)) {         // row alive -> apply its suppression
        unsigned nzi = nz[b * NPRE + row];
        ull m = 0;
        if (lane < 16 && ((nzi >> lane) & 1u))
          m = mask[((size_t)b * NPRE + row) * 16 + lane];
        remv |= m;
      }
    }
  }
  if (lane < 16) remv_out[b * 16 + lane] = remv;
}

// ---------------- K5: compact survivors, gather outputs -------------------
__global__ __launch_bounds__(1024) void k_final(
    const float* __restrict__ box, const float* __restrict__ cls,
    const int* __restrict__ topi, const ull* __restrict__ remv,
    float* __restrict__ out, int B) {
  int b = blockIdx.x;
  int p = threadIdx.x;                 // 0..1023
  int lane = p & 63, wid = p >> 6;
  ull rw = remv[b * 16 + wid];
  int alive = ((rw >> lane) & 1ULL) ? 0 : 1;
  int v = alive;
#pragma unroll
  for (int off = 1; off < 64; off <<= 1) {
    int t = __shfl_up(v, off, 64);
    if (lane >= off) v += t;
  }
  __shared__ int wtot[16], woff[17];
  if (lane == 63) wtot[wid] = v;
  __syncthreads();
  if (p == 0) {
    int acc = 0;
    for (int t = 0; t < 16; ++t) { woff[t] = acc; acc += wtot[t]; }
    woff[16] = acc;
  }
  __syncthreads();
  int excl = v - alive + woff[wid];
  int total = woff[16];
  float* rois   = out;
  float* scores = out + (size_t)B * NPOST * 7;
  float* labels = scores + (size_t)B * NPOST;
  float* logits = labels + (size_t)B * NPOST;
  if (alive && excl < NPOST) {
    int s = excl;
    int orig = topi[b * NPRE + p];
    const float* bb = box + ((size_t)b * NBOX + orig) * 7;
    float* ro = rois + ((size_t)b * NPOST + s) * 7;
#pragma unroll
    for (int c = 0; c < 7; ++c) ro[c] = bb[c];
    const float* cc = cls + ((size_t)b * NBOX + orig) * 3;
    float l0 = cc[0], l1 = cc[1], l2 = cc[2];
    float m = fmaxf(l0, fmaxf(l1, l2));
    int lab = (l0 == m) ? 0 : ((l1 == m) ? 1 : 2);   // argmax: first max
    scores[b * NPOST + s] = m;
    labels[b * NPOST + s] = (float)(lab + 1);
    float* lg = logits + ((size_t)b * NPOST + s) * 3;
    lg[0] = l0; lg[1] = l1; lg[2] = l2;
  }
  if (p < NPOST && p >= total) {       // invalid slots: zeros, label 1
    float* ro = rois + ((size_t)b * NPOST + p) * 7;
#pragma unroll
    for (int c = 0; c < 7; ++c) ro[c] = 0.f;
    scores[b * NPOST + p] = 0.f;
    labels[b * NPOST + p] = 1.f;
    float* lg = logits + ((size_t)b * NPOST + p) * 3;
    lg[0] = 0.f; lg[1] = 0.f; lg[2] = 0.f;
  }
}

extern "C" void kernel_launch(void* const* d_in, const int* in_sizes, int n_in,
                              void* d_out, int out_size, void* d_ws, size_t ws_size,
                              hipStream_t stream) {
  const float* box = (const float*)d_in[0];
  const float* cls = (const float*)d_in[1];
  float* out = (float*)d_out;
  int B = in_sizes[0] / (NBOX * 7);    // == 2

  char* w = (char*)d_ws;
  size_t off = 0;
  ull* cand        = (ull*)(w + off);      off += (size_t)B * NCAND * sizeof(ull);
  unsigned* candCt = (unsigned*)(w + off); off += (size_t)B * sizeof(unsigned);
  int* topi        = (int*)(w + off);      off += (size_t)B * NPRE * sizeof(int);
  off = (off + 63) & ~(size_t)63;
  float* binfo     = (float*)(w + off);    off += (size_t)B * NPRE * 16 * sizeof(float);
  ull* mask        = (ull*)(w + off);      off += (size_t)B * NPRE * 16 * sizeof(ull);
  unsigned* nz     = (unsigned*)(w + off); off += (size_t)B * NPRE * sizeof(unsigned);
  ull* remv        = (ull*)(w + off);      off += (size_t)B * 16 * sizeof(ull);
  (void)off; (void)ws_size; (void)out_size; (void)n_in;

  hipLaunchKernelGGL(k_hist,    dim3(B), dim3(1024), 0, stream, cls, cand, candCt, nz);
  hipLaunchKernelGGL(k_ranksel, dim3(NCAND / 64, B), dim3(64), 0, stream, box, cand, candCt, topi, binfo);
  hipLaunchKernelGGL(k_ioumask, dim3(B * NPRE * 16 / 4), dim3(256), 0, stream, binfo, mask, nz);
  hipLaunchKernelGGL(k_nms,     dim3(B), dim3(64), 0, stream, mask, nz, remv);
  hipLaunchKernelGGL(k_final,   dim3(B), dim3(1024), 0, stream, box, cls, topi, remv, out, B);
}

// Round 3
// 143.208 us; speedup vs baseline: 2.3028x; 1.1596x over previous
//
#include <hip/hip_runtime.h>
#include <hip/hip_bf16.h>
#include <math.h>

#define NBOX   16384
#define NPRE   1024
#define NPOST  512
#define NMS_TH 0.8f
#define DEN_EPS 1e-8f
#define NCAND  2048          // top-k candidate buffer
#define NBUCK  8192          // 13-bit histogram buckets
#define WMAX   (1u << 20)    // max worklist entries (4 MB)

typedef unsigned long long ull;

__device__ __forceinline__ unsigned mono_f32(float a) {
  unsigned u = __float_as_uint(a);
  return (u & 0x80000000u) ? ~u : (u | 0x80000000u);
}

// ---------------- K1: keys + histogram select + compact (one block/batch) ----
__global__ __launch_bounds__(1024) void k_hist(
    const float* __restrict__ cls, ull* __restrict__ cand,
    unsigned* __restrict__ candCount, unsigned* __restrict__ nz,
    ull* __restrict__ mask, unsigned* __restrict__ wcnt) {
  __shared__ unsigned hist[NBUCK];
  __shared__ unsigned ssum[1024];
  __shared__ unsigned thrT;
  __shared__ unsigned cnt;
  int b = blockIdx.x;
  int t = threadIdx.x;
  nz[b * NPRE + t] = 0u;                       // zero nz
  ull* mb = mask + (size_t)b * NPRE * 16;      // zero mask (OR-accumulated later)
#pragma unroll
  for (int k = 0; k < 16; ++k) mb[k * 1024 + t] = 0ull;
  if (b == 0 && t == 0) wcnt[0] = 0u;
#pragma unroll
  for (int k = 0; k < NBUCK / 1024; ++k) hist[t + k * 1024] = 0u;
  if (t == 0) cnt = 0u;
  __syncthreads();

  ull key[16];
#pragma unroll
  for (int k = 0; k < 16; ++k) {
    int i = k * 1024 + t;
    const float* cc = cls + ((size_t)b * NBOX + i) * 3;
    float s = fmaxf(cc[0], fmaxf(cc[1], cc[2]));
    unsigned u = mono_f32(s);
    key[k] = ((ull)u << 14) | (ull)(16383 - i);
    atomicAdd(&hist[u >> 19], 1u);
  }
  __syncthreads();

  unsigned s8 = 0;
#pragma unroll
  for (int k = 0; k < 8; ++k) s8 += hist[t * 8 + k];
  ssum[t] = s8;
  __syncthreads();
  for (int off = 1; off < 1024; off <<= 1) {
    unsigned v = ssum[t] + ((t + off < 1024) ? ssum[t + off] : 0u);
    __syncthreads();
    ssum[t] = v;
    __syncthreads();
  }
  unsigned Sown = ssum[t];
  unsigned Snxt = (t < 1023) ? ssum[t + 1] : 0u;
  if (Sown >= NPRE && Snxt < NPRE) {           // unique boundary group
    unsigned c = Snxt;
    unsigned T = t * 8;
    for (int k = 7; k >= 0; --k) {
      c += hist[t * 8 + k];
      if (c >= NPRE) { T = t * 8 + k; break; }
    }
    thrT = T;
  }
  __syncthreads();
  unsigned T = thrT;
#pragma unroll
  for (int k = 0; k < 16; ++k) {
    unsigned bkt = (unsigned)(key[k] >> 33);
    if (bkt >= T) {
      unsigned pos = atomicAdd(&cnt, 1u);
      if (pos < NCAND) cand[(size_t)b * NCAND + pos] = key[k];
    }
  }
  __syncthreads();
  if (t == 0) candCount[b] = (cnt < NCAND) ? cnt : NCAND;
}

// ---------------- K2: rank candidates, emit topi + per-box geometry ----------
// binfo row (16 floats): x,y,dx,dy,cos,sin,cx[4],cy[4],circumrad,area
__global__ __launch_bounds__(256) void k_ranksel(
    const float* __restrict__ box, const ull* __restrict__ cand,
    const unsigned* __restrict__ candCount,
    int* __restrict__ topi, float* __restrict__ binfo) {
  __shared__ ull lk[NCAND];
  int b = blockIdx.y;
  int tid = threadIdx.x;
  int j = blockIdx.x * 256 + tid;              // 0..2047
  unsigned C = candCount[b];
#pragma unroll
  for (int k = 0; k < NCAND / 256; ++k) {
    int idx = k * 256 + tid;
    lk[idx] = ((unsigned)idx < C) ? cand[(size_t)b * NCAND + idx] : 0ULL;
  }
  __syncthreads();
  ull my = ((unsigned)j < C) ? lk[j] : 0ULL;
  int r = 0;
  const ulonglong2* p2 = (const ulonglong2*)lk;
#pragma unroll 8
  for (int k = 0; k < NCAND / 2; ++k) {
    ulonglong2 kk = p2[k];
    r += (kk.x > my) ? 1 : 0;
    r += (kk.y > my) ? 1 : 0;
  }
  if ((unsigned)j >= C || r >= NPRE) return;
  int i = 16383 - (int)(my & 0x3FFFULL);
  topi[b * NPRE + r] = i;
  const float* bp = box + ((size_t)b * NBOX + i) * 7;
  float x = bp[0], y = bp[1], dx = bp[3], dy = bp[4], ry = bp[6];
  float c = cosf(ry), s = sinf(ry);
  float* o = binfo + ((size_t)b * NPRE + r) * 16;
  o[0] = x; o[1] = y; o[2] = dx; o[3] = dy; o[4] = c; o[5] = s;
  const float offx[4] = {0.5f, -0.5f, -0.5f, 0.5f};
  const float offy[4] = {0.5f, 0.5f, -0.5f, -0.5f};
#pragma unroll
  for (int k = 0; k < 4; ++k) {
    float lx = dx * offx[k], ly = dy * offy[k];
    o[6 + k]  = x + lx * c - ly * s;
    o[10 + k] = y + lx * s + ly * c;
  }
  o[14] = 0.5f * sqrtf(dx * dx + dy * dy);
  o[15] = dx * dy;
}

// ---------------- exact rotated IoU > thresh, register-only (no sort) --------
// Reference semantics: stable argsort by (angle, idx) == successor chain on
// key = (mono(angle) << 5) | idx; polygon area = sum of cross(p, succ(p)).
__device__ bool iou_exact_gt(const float* __restrict__ Ab, const float* __restrict__ Bb) {
  float ax = Ab[0], ay = Ab[1], bx = Bb[0], by = Bb[1];
  float aA = Ab[15], aB = Bb[15];
  float acx[4], acy[4], bcx[4], bcy[4];
#pragma unroll
  for (int k = 0; k < 4; ++k) {
    acx[k] = Ab[6 + k]; acy[k] = Ab[10 + k];
    bcx[k] = Bb[6 + k]; bcy[k] = Bb[10 + k];
  }
  float px[24], py[24];
  bool act[24];
#pragma unroll
  for (int p = 0; p < 4; ++p) {
    float A0x = acx[p], A0y = acy[p];
    float DAx = acx[(p + 1) & 3] - A0x, DAy = acy[(p + 1) & 3] - A0y;
#pragma unroll
    for (int q = 0; q < 4; ++q) {
      float B0x = bcx[q], B0y = bcy[q];
      float DBx = bcx[(q + 1) & 3] - B0x, DBy = bcy[(q + 1) & 3] - B0y;
      float den = DAx * DBy - DAy * DBx;
      float dxx = B0x - A0x, dyy = B0y - A0y;
      bool dok = fabsf(den) > DEN_EPS;
      float dens = dok ? den : 1.0f;
      float t = (dxx * DBy - dyy * DBx) / dens;
      float u = (dxx * DAy - dyy * DAx) / dens;
      int k = p * 4 + q;
      px[k] = A0x + t * DAx;
      py[k] = A0y + t * DAy;
      act[k] = dok && t >= 0.f && t <= 1.f && u >= 0.f && u <= 1.f;
    }
  }
  float cA = Ab[4], sA = Ab[5], cB = Bb[4], sB = Bb[5];
#pragma unroll
  for (int k = 0; k < 4; ++k) {       // corners of A in B
    float rx = acx[k] - bx, ry = acy[k] - by;
    float qx =  rx * cB + ry * sB, qy = -rx * sB + ry * cB;
    px[16 + k] = acx[k]; py[16 + k] = acy[k];
    act[16 + k] = (fabsf(qx) <= Bb[2] * 0.5f + 1e-5f) && (fabsf(qy) <= Bb[3] * 0.5f + 1e-5f);
  }
#pragma unroll
  for (int k = 0; k < 4; ++k) {       // corners of B in A
    float rx = bcx[k] - ax, ry = bcy[k] - ay;
    float qx =  rx * cA + ry * sA, qy = -rx * sA + ry * cA;
    px[20 + k] = bcx[k]; py[20 + k] = bcy[k];
    act[20 + k] = (fabsf(qx) <= Ab[2] * 0.5f + 1e-5f) && (fabsf(qy) <= Ab[3] * 0.5f + 1e-5f);
  }
  int cnt = 0; float sx = 0.f, sy = 0.f;
#pragma unroll
  for (int k = 0; k < 24; ++k)
    if (act[k]) { cnt++; sx += px[k]; sy += py[k]; }
  float fc = (float)(cnt > 1 ? cnt : 1);
  float cx0 = sx / fc, cy0 = sy / fc;
  ull key[24];
#pragma unroll
  for (int k = 0; k < 24; ++k) {
    float ang = atan2f(py[k] - cy0, px[k] - cx0);
    key[k] = act[k] ? ((((ull)mono_f32(ang)) << 5) | (ull)k) : ~0ull;
  }
  // global min key (== pts_s[0], the 'first' fill point)
  ull kmin = ~0ull; float fx = 0.f, fy = 0.f;
#pragma unroll
  for (int k = 0; k < 24; ++k) {
    bool lt = key[k] < kmin;
    kmin = lt ? key[k] : kmin;
    fx = lt ? px[k] : fx;
    fy = lt ? py[k] : fy;
  }
  float ssum = 0.f;
#pragma unroll
  for (int k = 0; k < 24; ++k) {
    ull myk = key[k];
    ull best = ~0ull; float nx = fx, ny = fy;   // default: wrap to first
#pragma unroll
    for (int j = 0; j < 24; ++j) {
      bool c = (key[j] > myk) && (key[j] < best);
      best = c ? key[j] : best;
      nx = c ? px[j] : nx;
      ny = c ? py[j] : ny;
    }
    float contrib = px[k] * ny - py[k] * nx;
    ssum += (myk != ~0ull) ? contrib : 0.f;
  }
  float inter = 0.5f * fabsf(ssum);
  float uni = aA + aB - inter;
  return inter / fmaxf(uni, 1e-6f) > NMS_TH;
}

// ---------------- K3a: cheap rejects -> compact worklist ---------------------
__global__ void k_pairs(const float* __restrict__ binfo, unsigned* __restrict__ wl,
                        unsigned* __restrict__ wcnt, unsigned wcap,
                        ull* __restrict__ mask, unsigned* __restrict__ nz) {
  int wv = (blockIdx.x * 256 + threadIdx.x) >> 6;
  int lane = threadIdx.x & 63;
  int w = wv & 15;
  int i = (wv >> 4) & (NPRE - 1);
  int b = wv >> 14;
  int j = w * 64 + lane;
  const float* base = binfo + (size_t)b * NPRE * 16;
  bool cand = false;
  if (w * 64 + 63 > i && j > i) {
    const float* Ab = base + (size_t)i * 16;
    const float* Bb = base + (size_t)j * 16;
    float ddx = Ab[0] - Bb[0], ddy = Ab[1] - Bb[1];
    float rr = Ab[14] + Bb[14] + 1e-3f;
    if (ddx * ddx + ddy * ddy <= rr * rr) {      // not provably disjoint
      float aA = Ab[15], aB = Bb[15];
      float mn = fminf(aA, aB), mx = fmaxf(aA, aB);
      if (mn > NMS_TH * mx) cand = true;         // not provably iou<=0.8
    }
  }
  ull bal = __ballot(cand);
  if (!bal) return;
  unsigned baseOff = 0;
  if (lane == 0) baseOff = atomicAdd(wcnt, (unsigned)__popcll(bal));
  baseOff = (unsigned)__shfl((int)baseOff, 0, 64);
  if (cand) {
    unsigned off = baseOff + (unsigned)__popcll(bal & ((1ull << lane) - 1ull));
    if (off < wcap) {
      wl[off] = ((unsigned)b << 20) | ((unsigned)i << 10) | (unsigned)j;
    } else {                                     // overflow fallback (never at this density)
      if (iou_exact_gt(base + (size_t)i * 16, base + (size_t)j * 16)) {
        atomicOr(&mask[((size_t)b * NPRE + i) * 16 + w], 1ull << lane);
        atomicOr(&nz[b * NPRE + i], 1u << w);
      }
    }
  }
}

// ---------------- K3b: exact IoU over dense worklist -------------------------
__global__ __launch_bounds__(256) void k_iou(
    const float* __restrict__ binfo, const unsigned* __restrict__ wl,
    const unsigned* __restrict__ wcnt, unsigned wcap,
    ull* __restrict__ mask, unsigned* __restrict__ nz) {
  unsigned n = wcnt[0];
  if (n > wcap) n = wcap;
  unsigned stride = gridDim.x * 256;
  for (unsigned t = blockIdx.x * 256 + threadIdx.x; t < n; t += stride) {
    unsigned pk = wl[t];
    unsigned b = pk >> 20, i = (pk >> 10) & 1023, j = pk & 1023;
    const float* base = binfo + (size_t)b * NPRE * 16;
    if (iou_exact_gt(base + (size_t)i * 16, base + (size_t)j * 16)) {
      atomicOr(&mask[((size_t)b * NPRE + i) * 16 + (j >> 6)], 1ull << (j & 63));
      atomicOr(&nz[b * NPRE + i], 1u << (j >> 6));
    }
  }
}

// ---------------- K4: sparse greedy NMS, one wave per batch ------------------
__global__ __launch_bounds__(64) void k_nms(const ull* __restrict__ mask,
                                            const unsigned* __restrict__ nz,
                                            ull* __restrict__ remv_out) {
  __shared__ ull rf[16];
  int b = blockIdx.x;
  int lane = threadIdx.x;
  for (int w = 0; w < 16; ++w) {
    unsigned v = nz[b * NPRE + w * 64 + lane];
    ull bb = __ballot(v != 0u);
    if (lane == 0) rf[w] = bb;
  }
  __syncthreads();
  ull remv = 0;                          // lane w<16 holds remv word w
  for (int w = 0; w < 16; ++w) {
    ull bb = rf[w];                      // wave-uniform
    while (bb) {
      int i = __ffsll(bb) - 1;
      bb &= bb - 1;
      int row = w * 64 + i;
      ull rw = __shfl(remv, w, 64);      // current remv word w (uniform)
      if (!((rw >> i) & 1ULL)) {         // row alive -> apply its suppression
        unsigned nzi = nz[b * NPRE + row];
        ull m = 0;
        if (lane < 16 && ((nzi >> lane) & 1u))
          m = mask[((size_t)b * NPRE + row) * 16 + lane];
        remv |= m;
      }
    }
  }
  if (lane < 16) remv_out[b * 16 + lane] = remv;
}

// ---------------- K5: compact survivors, gather outputs ----------------------
__global__ __launch_bounds__(1024) void k_final(
    const float* __restrict__ box, const float* __restrict__ cls,
    const int* __restrict__ topi, const ull* __restrict__ remv,
    float* __restrict__ out, int B) {
  int b = blockIdx.x;
  int p = threadIdx.x;                 // 0..1023
  int lane = p & 63, wid = p >> 6;
  ull rw = remv[b * 16 + wid];
  int alive = ((rw >> lane) & 1ULL) ? 0 : 1;
  int v = alive;
#pragma unroll
  for (int off = 1; off < 64; off <<= 1) {
    int t = __shfl_up(v, off, 64);
    if (lane >= off) v += t;
  }
  __shared__ int wtot[16], woff[17];
  if (lane == 63) wtot[wid] = v;
  __syncthreads();
  if (p == 0) {
    int acc = 0;
    for (int t = 0; t < 16; ++t) { woff[t] = acc; acc += wtot[t]; }
    woff[16] = acc;
  }
  __syncthreads();
  int excl = v - alive + woff[wid];
  int total = woff[16];
  float* rois   = out;
  float* scores = out + (size_t)B * NPOST * 7;
  float* labels = scores + (size_t)B * NPOST;
  float* logits = labels + (size_t)B * NPOST;
  if (alive && excl < NPOST) {
    int s = excl;
    int orig = topi[b * NPRE + p];
    const float* bb = box + ((size_t)b * NBOX + orig) * 7;
    float* ro = rois + ((size_t)b * NPOST + s) * 7;
#pragma unroll
    for (int c = 0; c < 7; ++c) ro[c] = bb[c];
    const float* cc = cls + ((size_t)b * NBOX + orig) * 3;
    float l0 = cc[0], l1 = cc[1], l2 = cc[2];
    float m = fmaxf(l0, fmaxf(l1, l2));
    int lab = (l0 == m) ? 0 : ((l1 == m) ? 1 : 2);   // argmax: first max
    scores[b * NPOST + s] = m;
    labels[b * NPOST + s] = (float)(lab + 1);
    float* lg = logits + ((size_t)b * NPOST + s) * 3;
    lg[0] = l0; lg[1] = l1; lg[2] = l2;
  }
  if (p < NPOST && p >= total) {       // invalid slots: zeros, label 1
    float* ro = rois + ((size_t)b * NPOST + p) * 7;
#pragma unroll
    for (int c = 0; c < 7; ++c) ro[c] = 0.f;
    scores[b * NPOST + p] = 0.f;
    labels[b * NPOST + p] = 1.f;
    float* lg = logits + ((size_t)b * NPOST + p) * 3;
    lg[0] = 0.f; lg[1] = 0.f; lg[2] = 0.f;
  }
}

extern "C" void kernel_launch(void* const* d_in, const int* in_sizes, int n_in,
                              void* d_out, int out_size, void* d_ws, size_t ws_size,
                              hipStream_t stream) {
  const float* box = (const float*)d_in[0];
  const float* cls = (const float*)d_in[1];
  float* out = (float*)d_out;
  int B = in_sizes[0] / (NBOX * 7);    // == 2

  char* w = (char*)d_ws;
  size_t off = 0;
  ull* cand        = (ull*)(w + off);      off += (size_t)B * NCAND * sizeof(ull);
  unsigned* candCt = (unsigned*)(w + off); off += (size_t)B * sizeof(unsigned);
  int* topi        = (int*)(w + off);      off += (size_t)B * NPRE * sizeof(int);
  off = (off + 63) & ~(size_t)63;
  float* binfo     = (float*)(w + off);    off += (size_t)B * NPRE * 16 * sizeof(float);
  ull* mask        = (ull*)(w + off);      off += (size_t)B * NPRE * 16 * sizeof(ull);
  unsigned* nz     = (unsigned*)(w + off); off += (size_t)B * NPRE * sizeof(unsigned);
  ull* remv        = (ull*)(w + off);      off += (size_t)B * 16 * sizeof(ull);
  unsigned* wcnt   = (unsigned*)(w + off); off += 64;
  unsigned* wl     = (unsigned*)(w + off);
  unsigned wcap = 0;
  if (ws_size > off) {
    size_t rem = (ws_size - off) / sizeof(unsigned);
    wcap = (rem < (size_t)WMAX) ? (unsigned)rem : WMAX;
  }
  (void)out_size; (void)n_in;

  hipLaunchKernelGGL(k_hist,    dim3(B), dim3(1024), 0, stream, cls, cand, candCt, nz, mask, wcnt);
  hipLaunchKernelGGL(k_ranksel, dim3(NCAND / 256, B), dim3(256), 0, stream, box, cand, candCt, topi, binfo);
  hipLaunchKernelGGL(k_pairs,   dim3(B * NPRE * 16 / 4), dim3(256), 0, stream, binfo, wl, wcnt, wcap, mask, nz);
  hipLaunchKernelGGL(k_iou,     dim3(64), dim3(256), 0, stream, binfo, wl, wcnt, wcap, mask, nz);
  hipLaunchKernelGGL(k_nms,     dim3(B), dim3(64), 0, stream, mask, nz, remv);
  hipLaunchKernelGGL(k_final,   dim3(B), dim3(1024), 0, stream, box, cls, topi, remv, out, B);
}